// Round 1
// baseline (2262.798 us; speedup 1.0000x reference)
//
#include <hip/hip_runtime.h>
#include <math.h>

#define Bsz 128
#define Tsz 256
#define Isz 256
#define Hsz 256
#define Lsz 4
#define Ssz 3
#define Mrows (Bsz*Tsz)   // 32768

constexpr int BM = 64, BN = 64, BK = 32;

// Fused "GRU" layer GEMM: computes gi = A @ W^T (+ biases) for the three
// 256-column slabs (r,z,n) and applies the gating, writing h (M x 256).
// grid.z = cur (0..2); per-cur strides passed in.
__global__ __launch_bounds__(256) void gemm_gru(
    const float* __restrict__ Abase, size_t a_stride,
    const float* __restrict__ Wbase, size_t w_stride,
    const float* __restrict__ bibase, size_t bi_stride,
    const float* __restrict__ bhbase, size_t bh_stride,
    float* __restrict__ Hout)
{
  __shared__ float As[BK][BM + 4];
  __shared__ float Wsh[3][BK][BN + 4];

  const int tid = threadIdx.x;
  const int z = blockIdx.z;
  const float* A  = Abase  + (size_t)z * a_stride;
  const float* W  = Wbase  + (size_t)z * w_stride;
  const float* bi = bibase + (size_t)z * bi_stride;
  const float* bh = bhbase + (size_t)z * bh_stride;
  const int m0 = blockIdx.x * BM;
  const int n0 = blockIdx.y * BN;

  const int lr = tid >> 3;         // 0..31 (row within tile)
  const int lc = (tid & 7) * 4;    // 0,4,..,28 (k within tile)

  float acc[3][4][4];
  #pragma unroll
  for (int s = 0; s < 3; s++)
    #pragma unroll
    for (int i = 0; i < 4; i++)
      #pragma unroll
      for (int j = 0; j < 4; j++) acc[s][i][j] = 0.f;

  const int tx = tid & 15, ty = tid >> 4;

  for (int k0 = 0; k0 < 256; k0 += BK) {
    // stage A tile (transposed into LDS)
    #pragma unroll
    for (int it = 0; it < 2; it++) {
      const int r = lr + it * 32;
      const float4 v = *(const float4*)(A + (size_t)(m0 + r) * 256 + k0 + lc);
      As[lc + 0][r] = v.x; As[lc + 1][r] = v.y;
      As[lc + 2][r] = v.z; As[lc + 3][r] = v.w;
    }
    // stage the three W slabs (rows n, n+256, n+512)
    #pragma unroll
    for (int s = 0; s < 3; s++) {
      #pragma unroll
      for (int it = 0; it < 2; it++) {
        const int r = lr + it * 32;
        const float4 v = *(const float4*)(W + (size_t)(s * Hsz + n0 + r) * 256 + k0 + lc);
        Wsh[s][lc + 0][r] = v.x; Wsh[s][lc + 1][r] = v.y;
        Wsh[s][lc + 2][r] = v.z; Wsh[s][lc + 3][r] = v.w;
      }
    }
    __syncthreads();
    #pragma unroll
    for (int kk = 0; kk < BK; kk++) {
      const float4 a  = *(const float4*)&As[kk][ty * 4];
      const float4 w0 = *(const float4*)&Wsh[0][kk][tx * 4];
      const float4 w1 = *(const float4*)&Wsh[1][kk][tx * 4];
      const float4 w2 = *(const float4*)&Wsh[2][kk][tx * 4];
      const float av[4]  = {a.x, a.y, a.z, a.w};
      const float wv0[4] = {w0.x, w0.y, w0.z, w0.w};
      const float wv1[4] = {w1.x, w1.y, w1.z, w1.w};
      const float wv2[4] = {w2.x, w2.y, w2.z, w2.w};
      #pragma unroll
      for (int i = 0; i < 4; i++) {
        #pragma unroll
        for (int j = 0; j < 4; j++) {
          acc[0][i][j] += av[i] * wv0[j];
          acc[1][i][j] += av[i] * wv1[j];
          acc[2][i][j] += av[i] * wv2[j];
        }
      }
    }
    __syncthreads();
  }

  // epilogue: gating
  #pragma unroll
  for (int i = 0; i < 4; i++) {
    const int m = m0 + ty * 4 + i;
    float4 o;
    float* op = (float*)&o;
    #pragma unroll
    for (int j = 0; j < 4; j++) {
      const int n = n0 + tx * 4 + j;
      const float gr = acc[0][i][j] + bi[n]           + bh[n];
      const float gz = acc[1][i][j] + bi[Hsz + n]     + bh[Hsz + n];
      const float gn = acc[2][i][j] + bi[2 * Hsz + n];
      const float r  = 1.f / (1.f + expf(-gr));
      const float zz = 1.f / (1.f + expf(-gz));
      const float nn = tanhf(gn + r * bh[2 * Hsz + n]);
      op[j] = (1.f - zz) * nn;
    }
    *(float4*)(Hout + ((size_t)z * Mrows + m) * 256 + n0 + tx * 4) = o;
  }
}

// Per-layer dot products feeding attention/selection:
// e[c,t,b,l,j] = h . w_lw[j]   (j=0..3)
// p[c,t,b,l,s] = h . w_sel[s, 0:H]  (s=0..2)
__global__ __launch_bounds__(256) void ep_kernel(
    const float* __restrict__ hbuf, const float* __restrict__ w_lw,
    const float* __restrict__ w_sel, int layer,
    float* __restrict__ e, float* __restrict__ p)
{
  const int wv = threadIdx.x >> 6, ln = threadIdx.x & 63;
  const size_t mg = (size_t)blockIdx.x * 4 + wv;  // 0..3*M-1
  const float4 h = *(const float4*)(hbuf + mg * 256 + ln * 4);
  float d[7];
  #pragma unroll
  for (int j = 0; j < 4; j++) {
    const float4 w = *(const float4*)(w_lw + j * 256 + ln * 4);
    d[j] = h.x * w.x + h.y * w.y + h.z * w.z + h.w * w.w;
  }
  #pragma unroll
  for (int q = 0; q < 3; q++) {
    const float4 w = *(const float4*)(w_sel + q * (Hsz + Isz) + ln * 4);
    d[4 + q] = h.x * w.x + h.y * w.y + h.z * w.z + h.w * w.w;
  }
  #pragma unroll
  for (int off = 32; off; off >>= 1)
    #pragma unroll
    for (int i = 0; i < 7; i++) d[i] += __shfl_xor(d[i], off);
  if (ln == 0) {
    const int c = (int)(mg / Mrows);
    const int m = (int)(mg % Mrows);
    const int b = m >> 8, t = m & 255;   // m = b*T + t
    const size_t base = ((size_t)c * Tsz + t) * Bsz + b;
    #pragma unroll
    for (int j = 0; j < 4; j++) e[base * 16 + layer * 4 + j] = d[j];
    #pragma unroll
    for (int q = 0; q < 3; q++) p[base * 12 + layer * 3 + q] = d[4 + q];
  }
}

// score_h[c,t,s] = sum_b sum_l softmax_l(attn)[b,l] * p[c,t,b,l,s]
__global__ __launch_bounds__(128) void attn_finish(
    const float* __restrict__ e, const float* __restrict__ p,
    const float* __restrict__ hidden, const float* __restrict__ b_lw,
    float* __restrict__ score_h)
{
  const int t = blockIdx.x, c = blockIdx.y;
  const int b = threadIdx.x;
  const float* eb = e + ((size_t)(c * Tsz + t) * Bsz + b) * 16;
  const float* pb = p + ((size_t)(c * Tsz + t) * Bsz + b) * 12;
  const float* hb = hidden + b * 16;
  const float bl0 = b_lw[0], bl1 = b_lw[1], bl2 = b_lw[2], bl3 = b_lw[3];
  float attn[4];
  #pragma unroll
  for (int i = 0; i < 4; i++) {
    attn[i] = hb[i * 4 + 0] * (eb[i * 4 + 0] + bl0)
            + hb[i * 4 + 1] * (eb[i * 4 + 1] + bl1)
            + hb[i * 4 + 2] * (eb[i * 4 + 2] + bl2)
            + hb[i * 4 + 3] * (eb[i * 4 + 3] + bl3);
  }
  const float mx = fmaxf(fmaxf(attn[0], attn[1]), fmaxf(attn[2], attn[3]));
  float ex[4], sum = 0.f;
  #pragma unroll
  for (int i = 0; i < 4; i++) { ex[i] = expf(attn[i] - mx); sum += ex[i]; }
  const float inv = 1.f / sum;
  float sc[3];
  #pragma unroll
  for (int s = 0; s < 3; s++) {
    float v = 0.f;
    #pragma unroll
    for (int i = 0; i < 4; i++) v += ex[i] * pb[i * 3 + s];
    sc[s] = v * inv;
  }
  #pragma unroll
  for (int off = 32; off; off >>= 1)
    #pragma unroll
    for (int s = 0; s < 3; s++) sc[s] += __shfl_xor(sc[s], off);
  __shared__ float red[2][3];
  const int wv = threadIdx.x >> 6, ln = threadIdx.x & 63;
  if (ln == 0) { red[wv][0] = sc[0]; red[wv][1] = sc[1]; red[wv][2] = sc[2]; }
  __syncthreads();
  if (threadIdx.x == 0) {
    #pragma unroll
    for (int s = 0; s < 3; s++)
      score_h[((size_t)c * Tsz + t) * 3 + s] = red[0][s] + red[1][s];
  }
}

// xs[t,s] = (sum_b x[b,t,:]) . w_sel[s, H:] + B*b_sel[s]
__global__ __launch_bounds__(256) void xs_kernel(
    const float* __restrict__ x, const float* __restrict__ w_sel,
    const float* __restrict__ b_sel, float* __restrict__ xs)
{
  const int t = blockIdx.x, k = threadIdx.x;
  float s = 0.f;
  for (int b = 0; b < Bsz; b++) s += x[((size_t)b * Tsz + t) * Isz + k];
  float pr[3];
  #pragma unroll
  for (int q = 0; q < 3; q++) pr[q] = s * w_sel[q * (Hsz + Isz) + Hsz + k];
  #pragma unroll
  for (int off = 32; off; off >>= 1)
    #pragma unroll
    for (int q = 0; q < 3; q++) pr[q] += __shfl_xor(pr[q], off);
  __shared__ float red[4][3];
  const int wv = k >> 6, ln = k & 63;
  if (ln == 0) { red[wv][0] = pr[0]; red[wv][1] = pr[1]; red[wv][2] = pr[2]; }
  __syncthreads();
  if (k == 0) {
    #pragma unroll
    for (int q = 0; q < 3; q++)
      xs[t * 3 + q] = red[0][q] + red[1][q] + red[2][q] + red[3][q]
                      + (float)Bsz * b_sel[q];
  }
}

// Transition table + serial 255-step chain (single block).
__global__ __launch_bounds__(256) void select_kernel(
    const float* __restrict__ score_h, const float* __restrict__ xs,
    int* __restrict__ cur)
{
  __shared__ int f[Tsz][3];
  const int tid = threadIdx.x;
  for (int u = tid; u < (Tsz - 1) * 3; u += 256) {
    const int t = 1 + u / 3, c = u % 3;
    const float* sh = score_h + ((size_t)c * Tsz + (t - 1)) * 3;
    const float* xr = xs + t * 3;
    const float v0 = sh[0] + xr[0];
    const float v1 = sh[1] + xr[1];
    const float v2 = sh[2] + xr[2];
    int best = 0; float bv = v0;
    if (v1 > bv) { bv = v1; best = 1; }
    if (v2 > bv) { bv = v2; best = 2; }
    f[t][c] = best;
  }
  __syncthreads();
  if (tid == 0) {
    int c = 0; cur[0] = 0;
    for (int t = 1; t < Tsz; t++) { c = f[t][c]; cur[t] = c; }
  }
}

// outputs[b,t,:] = h3[cur[t], b*T+t, :]; h_final[b,:] = h3[cur[T-1], b*T+T-1, :]
__global__ __launch_bounds__(256) void gather_out(
    const float* __restrict__ h3, const int* __restrict__ cur,
    float* __restrict__ out)
{
  const size_t idx = ((size_t)blockIdx.x * 256 + threadIdx.x) * 4;
  const size_t BTH = (size_t)Bsz * Tsz * Hsz;
  int b, t, h;
  if (idx < BTH) {
    b = (int)(idx >> 16);
    const int rem = (int)(idx & 65535);
    t = rem >> 8; h = rem & 255;
  } else {
    const size_t r2 = idx - BTH;
    b = (int)(r2 >> 8); h = (int)(r2 & 255); t = Tsz - 1;
  }
  const int c = cur[t];
  const float4 v = *(const float4*)(h3 + (((size_t)c * Mrows + (size_t)b * Tsz + t) * Hsz + h));
  *(float4*)(out + idx) = v;
}

extern "C" void kernel_launch(void* const* d_in, const int* in_sizes, int n_in,
                              void* d_out, int out_size, void* d_ws, size_t ws_size,
                              hipStream_t stream) {
  const float* x      = (const float*)d_in[0];
  const float* hidden = (const float*)d_in[1];
  const float* w_ih0  = (const float*)d_in[2];
  const float* b_ih0  = (const float*)d_in[3];
  const float* b_hh0  = (const float*)d_in[4];
  const float* w_ih   = (const float*)d_in[5];
  const float* b_ih   = (const float*)d_in[6];
  const float* b_hh   = (const float*)d_in[7];
  const float* w_lw   = (const float*)d_in[8];
  const float* b_lw   = (const float*)d_in[9];
  const float* w_sel  = (const float*)d_in[10];
  const float* b_sel  = (const float*)d_in[11];
  float* out = (float*)d_out;

  float* ws = (float*)d_ws;
  const size_t SZbuf = (size_t)3 * Mrows * Hsz;      // 25,165,824 floats
  float* bufA    = ws;
  float* bufB    = bufA + SZbuf;
  float* e       = bufB + SZbuf;                      // 3*T*B*16
  float* p       = e + (size_t)3 * Tsz * Bsz * 16;    // 3*T*B*12
  float* score_h = p + (size_t)3 * Tsz * Bsz * 12;    // 3*T*3
  float* xsb     = score_h + 3 * Tsz * 3;             // T*3
  int*   curb    = (int*)(xsb + Tsz * 3);             // T ints

  dim3 ggrid(Mrows / BM, Hsz / BN, 3);

  // layer 0 (input x shared across cur)
  gemm_gru<<<ggrid, 256, 0, stream>>>(x, (size_t)0,
                                      w_ih0, (size_t)768 * 256,
                                      b_ih0, (size_t)768,
                                      b_hh0, (size_t)768, bufA);
  ep_kernel<<<(3 * Mrows) / 4, 256, 0, stream>>>(bufA, w_lw, w_sel, 0, e, p);

  const size_t wst = (size_t)3 * 768 * 256, bst = (size_t)3 * 768;
  float* ping = bufA; float* pong = bufB;
  for (int l = 1; l < 4; l++) {
    gemm_gru<<<ggrid, 256, 0, stream>>>(ping, (size_t)Mrows * Hsz,
                                        w_ih + (size_t)(l - 1) * 768 * 256, wst,
                                        b_ih + (size_t)(l - 1) * 768, bst,
                                        b_hh + (size_t)(l - 1) * 768, bst, pong);
    ep_kernel<<<(3 * Mrows) / 4, 256, 0, stream>>>(pong, w_lw, w_sel, l, e, p);
    float* tmp = ping; ping = pong; pong = tmp;
  }
  float* h3 = ping;  // last-written buffer (bufB)

  attn_finish<<<dim3(Tsz, 3), 128, 0, stream>>>(e, p, hidden, b_lw, score_h);
  xs_kernel<<<Tsz, 256, 0, stream>>>(x, w_sel, b_sel, xsb);
  select_kernel<<<1, 256, 0, stream>>>(score_h, xsb, curb);
  gather_out<<<8224, 256, 0, stream>>>(h3, curb, out);
}

// Round 2
// 893.823 us; speedup vs baseline: 2.5316x; 2.5316x over previous
//
#include <hip/hip_runtime.h>
#include <math.h>

#define Bsz 128
#define Tsz 256
#define Isz 256
#define Hsz 256
#define Lsz 4
#define Ssz 3
#define Mrows (Bsz*Tsz)   // 32768

using bf16x8 = __attribute__((ext_vector_type(8))) short;
using f32x4  = __attribute__((ext_vector_type(4))) float;

__device__ inline unsigned short f2b_rne(float f) {
  union { float f; unsigned u; } v; v.f = f;
  unsigned r = v.u + 0x7FFF + ((v.u >> 16) & 1);
  return (unsigned short)(r >> 16);
}
__device__ inline float b2f(unsigned short s) {
  union { float f; unsigned u; } v; v.u = ((unsigned)s) << 16; return v.f;
}
__device__ inline void splitf(float x, unsigned short& hi, unsigned short& lo) {
  hi = f2b_rne(x);
  lo = f2b_rne(x - b2f(hi));
}

// ---------------- weight split: fp32 -> (hi, lo) bf16 planes ----------------
__global__ __launch_bounds__(256) void split4_kernel(
    const float* __restrict__ src, unsigned short* __restrict__ hi,
    unsigned short* __restrict__ lo, int n4)
{
  const int idx = blockIdx.x * 256 + threadIdx.x;
  if (idx >= n4) return;
  const float4 v = *(const float4*)(src + (size_t)idx * 4);
  unsigned short h[4], l[4];
  splitf(v.x, h[0], l[0]); splitf(v.y, h[1], l[1]);
  splitf(v.z, h[2], l[2]); splitf(v.w, h[3], l[3]);
  *(ushort4*)(hi + (size_t)idx * 4) = *(ushort4*)h;
  *(ushort4*)(lo + (size_t)idx * 4) = *(ushort4*)l;
}

// ---------------- fused GRU-layer GEMM, split-bf16 MFMA ----------------
// C_slab = A @ W_slab^T for slabs r/z/n, gating fused, h written as hi/lo planes.
// grid: (M/128, 256/64, 3 cur). block 256 = 4 waves.
template<bool AF32>
__global__ __launch_bounds__(256, 2) void gemm_gru_mfma(
    const float* __restrict__ Af,
    const unsigned short* __restrict__ Ahi_g,
    const unsigned short* __restrict__ Alo_g,
    size_t a_cur_stride,
    const unsigned short* __restrict__ Whi_g,
    const unsigned short* __restrict__ Wlo_g,
    size_t w_cur_stride,
    const float* __restrict__ bi_g, size_t bi_stride,
    const float* __restrict__ bh_g, size_t bh_stride,
    unsigned short* __restrict__ Hhi, unsigned short* __restrict__ Hlo)
{
  // LDS: chunk-major, rows padded so (rows*4 dwords) % 32 == 8 -> conflict-free b128
  __shared__ unsigned short AhS[4 * 130 * 8];
  __shared__ unsigned short AlS[4 * 130 * 8];
  __shared__ unsigned short WhS[3 * 4 * 66 * 8];
  __shared__ unsigned short WlS[3 * 4 * 66 * 8];

  const int tid = threadIdx.x;
  const int cu  = blockIdx.z;
  const int m0  = blockIdx.x * 128;
  const int n0  = blockIdx.y * 64;

  const unsigned short* Whi = Whi_g + (size_t)cu * w_cur_stride;
  const unsigned short* Wlo = Wlo_g + (size_t)cu * w_cur_stride;
  const unsigned short* Ahi = AF32 ? nullptr : (Ahi_g + (size_t)cu * a_cur_stride);
  const unsigned short* Alo = AF32 ? nullptr : (Alo_g + (size_t)cu * a_cur_stride);
  const float* bi = bi_g + (size_t)cu * bi_stride;
  const float* bh = bh_g + (size_t)cu * bh_stride;

  const int lane = tid & 63;
  const int wv   = tid >> 6;
  const int q    = lane >> 4;      // k-chunk for frags
  const int c    = lane & 15;      // row/col within frag
  const int mb   = wv * 32;        // wave's row base within 128-tile

  f32x4 acc[3][2][4];
  #pragma unroll
  for (int s = 0; s < 3; s++)
    #pragma unroll
    for (int mi = 0; mi < 2; mi++)
      #pragma unroll
      for (int ni = 0; ni < 4; ni++)
        acc[s][mi][ni] = (f32x4)0.f;

  for (int k0 = 0; k0 < 256; k0 += 32) {
    // ---- stage A tile (128 x 32, hi+lo) ----
    #pragma unroll
    for (int i = 0; i < 2; i++) {
      const int idx = tid + i * 256;       // 0..511
      const int row = idx >> 2, ch = idx & 3;
      const int loff = (ch * 130 + row) * 8;
      if (AF32) {
        const float* ag = Af + (size_t)(m0 + row) * 256 + k0 + ch * 8;
        const float4 v0 = *(const float4*)ag;
        const float4 v1 = *(const float4*)(ag + 4);
        unsigned short hh[8], ll[8];
        splitf(v0.x, hh[0], ll[0]); splitf(v0.y, hh[1], ll[1]);
        splitf(v0.z, hh[2], ll[2]); splitf(v0.w, hh[3], ll[3]);
        splitf(v1.x, hh[4], ll[4]); splitf(v1.y, hh[5], ll[5]);
        splitf(v1.z, hh[6], ll[6]); splitf(v1.w, hh[7], ll[7]);
        *(uint4*)&AhS[loff] = *(uint4*)hh;
        *(uint4*)&AlS[loff] = *(uint4*)ll;
      } else {
        const size_t g = (size_t)(m0 + row) * 256 + k0 + ch * 8;
        *(uint4*)&AhS[loff] = *(const uint4*)&Ahi[g];
        *(uint4*)&AlS[loff] = *(const uint4*)&Alo[g];
      }
    }
    // ---- stage W tiles (3 slabs x 64 x 32, hi+lo) ----
    #pragma unroll
    for (int i = 0; i < 3; i++) {
      const int idx = tid + i * 256;       // 0..767
      const int s = idx >> 8, rr = (idx >> 2) & 63, ch = idx & 3;
      const size_t g = (size_t)(s * 256 + n0 + rr) * 256 + k0 + ch * 8;
      const int loff = ((s * 4 + ch) * 66 + rr) * 8;
      *(uint4*)&WhS[loff] = *(const uint4*)&Whi[g];
      *(uint4*)&WlS[loff] = *(const uint4*)&Wlo[g];
    }
    __syncthreads();

    const bf16x8 ah0 = *(const bf16x8*)&AhS[(q * 130 + mb + c) * 8];
    const bf16x8 ah1 = *(const bf16x8*)&AhS[(q * 130 + mb + 16 + c) * 8];
    const bf16x8 al0 = *(const bf16x8*)&AlS[(q * 130 + mb + c) * 8];
    const bf16x8 al1 = *(const bf16x8*)&AlS[(q * 130 + mb + 16 + c) * 8];

    #pragma unroll
    for (int s = 0; s < 3; s++) {
      #pragma unroll
      for (int ni = 0; ni < 4; ni++) {
        const int woff = ((s * 4 + q) * 66 + ni * 16 + c) * 8;
        const bf16x8 wh = *(const bf16x8*)&WhS[woff];
        const bf16x8 wl = *(const bf16x8*)&WlS[woff];
        acc[s][0][ni] = __builtin_amdgcn_mfma_f32_16x16x32_bf16(ah0, wh, acc[s][0][ni], 0, 0, 0);
        acc[s][1][ni] = __builtin_amdgcn_mfma_f32_16x16x32_bf16(ah1, wh, acc[s][1][ni], 0, 0, 0);
        acc[s][0][ni] = __builtin_amdgcn_mfma_f32_16x16x32_bf16(al0, wh, acc[s][0][ni], 0, 0, 0);
        acc[s][1][ni] = __builtin_amdgcn_mfma_f32_16x16x32_bf16(al1, wh, acc[s][1][ni], 0, 0, 0);
        acc[s][0][ni] = __builtin_amdgcn_mfma_f32_16x16x32_bf16(ah0, wl, acc[s][0][ni], 0, 0, 0);
        acc[s][1][ni] = __builtin_amdgcn_mfma_f32_16x16x32_bf16(ah1, wl, acc[s][1][ni], 0, 0, 0);
      }
    }
    __syncthreads();
  }

  // ---- epilogue: gating, split h into bf16 hi/lo planes ----
  float bir[4], biz[4], bin_[4], bhr[4], bhz[4], bhn[4];
  #pragma unroll
  for (int ni = 0; ni < 4; ni++) {
    const int n = n0 + ni * 16 + c;
    bir[ni] = bi[n];       bhr[ni] = bh[n];
    biz[ni] = bi[256 + n]; bhz[ni] = bh[256 + n];
    bin_[ni] = bi[512 + n]; bhn[ni] = bh[512 + n];
  }
  #pragma unroll
  for (int mi = 0; mi < 2; mi++) {
    #pragma unroll
    for (int reg = 0; reg < 4; reg++) {
      const int m = m0 + mb + mi * 16 + q * 4 + reg;
      const size_t rowbase = ((size_t)cu * Mrows + m) * 256;
      #pragma unroll
      for (int ni = 0; ni < 4; ni++) {
        const float gr = acc[0][mi][ni][reg] + bir[ni] + bhr[ni];
        const float gz = acc[1][mi][ni][reg] + biz[ni] + bhz[ni];
        const float gn = acc[2][mi][ni][reg] + bin_[ni];
        const float r  = 1.f / (1.f + expf(-gr));
        const float zz = 1.f / (1.f + expf(-gz));
        const float nn = tanhf(gn + r * bhn[ni]);
        const float h  = (1.f - zz) * nn;
        unsigned short hi, lo; splitf(h, hi, lo);
        Hhi[rowbase + n0 + ni * 16 + c] = hi;
        Hlo[rowbase + n0 + ni * 16 + c] = lo;
      }
    }
  }
}

// ---------------- per-layer dot products (e, p) ----------------
__global__ __launch_bounds__(256) void ep_kernel(
    const unsigned short* __restrict__ Hhi, const unsigned short* __restrict__ Hlo,
    const float* __restrict__ w_lw, const float* __restrict__ w_sel, int layer,
    float* __restrict__ e, float* __restrict__ p)
{
  const int wv = threadIdx.x >> 6, ln = threadIdx.x & 63;
  const size_t mg = (size_t)blockIdx.x * 4 + wv;  // 0..3*M-1
  const ushort4 vh = *(const ushort4*)(Hhi + mg * 256 + ln * 4);
  const ushort4 vl = *(const ushort4*)(Hlo + mg * 256 + ln * 4);
  float4 h;
  h.x = b2f(vh.x) + b2f(vl.x); h.y = b2f(vh.y) + b2f(vl.y);
  h.z = b2f(vh.z) + b2f(vl.z); h.w = b2f(vh.w) + b2f(vl.w);
  float d[7];
  #pragma unroll
  for (int j = 0; j < 4; j++) {
    const float4 w = *(const float4*)(w_lw + j * 256 + ln * 4);
    d[j] = h.x * w.x + h.y * w.y + h.z * w.z + h.w * w.w;
  }
  #pragma unroll
  for (int qq = 0; qq < 3; qq++) {
    const float4 w = *(const float4*)(w_sel + qq * (Hsz + Isz) + ln * 4);
    d[4 + qq] = h.x * w.x + h.y * w.y + h.z * w.z + h.w * w.w;
  }
  #pragma unroll
  for (int off = 32; off; off >>= 1)
    #pragma unroll
    for (int i = 0; i < 7; i++) d[i] += __shfl_xor(d[i], off);
  if (ln == 0) {
    const int cc = (int)(mg / Mrows);
    const int m = (int)(mg % Mrows);
    const int b = m >> 8, t = m & 255;
    const size_t base = ((size_t)cc * Tsz + t) * Bsz + b;
    #pragma unroll
    for (int j = 0; j < 4; j++) e[base * 16 + layer * 4 + j] = d[j];
    #pragma unroll
    for (int qq = 0; qq < 3; qq++) p[base * 12 + layer * 3 + qq] = d[4 + qq];
  }
}

// ---------------- softmax-attention + batch-reduced selector scores ----------------
__global__ __launch_bounds__(128) void attn_finish(
    const float* __restrict__ e, const float* __restrict__ p,
    const float* __restrict__ hidden, const float* __restrict__ b_lw,
    float* __restrict__ score_h)
{
  const int t = blockIdx.x, cc = blockIdx.y;
  const int b = threadIdx.x;
  const float* eb = e + ((size_t)(cc * Tsz + t) * Bsz + b) * 16;
  const float* pb = p + ((size_t)(cc * Tsz + t) * Bsz + b) * 12;
  const float* hb = hidden + b * 16;
  const float bl0 = b_lw[0], bl1 = b_lw[1], bl2 = b_lw[2], bl3 = b_lw[3];
  float attn[4];
  #pragma unroll
  for (int i = 0; i < 4; i++) {
    attn[i] = hb[i * 4 + 0] * (eb[i * 4 + 0] + bl0)
            + hb[i * 4 + 1] * (eb[i * 4 + 1] + bl1)
            + hb[i * 4 + 2] * (eb[i * 4 + 2] + bl2)
            + hb[i * 4 + 3] * (eb[i * 4 + 3] + bl3);
  }
  const float mx = fmaxf(fmaxf(attn[0], attn[1]), fmaxf(attn[2], attn[3]));
  float ex[4], sum = 0.f;
  #pragma unroll
  for (int i = 0; i < 4; i++) { ex[i] = expf(attn[i] - mx); sum += ex[i]; }
  const float inv = 1.f / sum;
  float sc[3];
  #pragma unroll
  for (int s = 0; s < 3; s++) {
    float v = 0.f;
    #pragma unroll
    for (int i = 0; i < 4; i++) v += ex[i] * pb[i * 3 + s];
    sc[s] = v * inv;
  }
  #pragma unroll
  for (int off = 32; off; off >>= 1)
    #pragma unroll
    for (int s = 0; s < 3; s++) sc[s] += __shfl_xor(sc[s], off);
  __shared__ float red[2][3];
  const int wv = threadIdx.x >> 6, ln = threadIdx.x & 63;
  if (ln == 0) { red[wv][0] = sc[0]; red[wv][1] = sc[1]; red[wv][2] = sc[2]; }
  __syncthreads();
  if (threadIdx.x == 0) {
    #pragma unroll
    for (int s = 0; s < 3; s++)
      score_h[((size_t)cc * Tsz + t) * 3 + s] = red[0][s] + red[1][s];
  }
}

// ---------------- xs[t,s] ----------------
__global__ __launch_bounds__(256) void xs_kernel(
    const float* __restrict__ x, const float* __restrict__ w_sel,
    const float* __restrict__ b_sel, float* __restrict__ xs)
{
  const int t = blockIdx.x, k = threadIdx.x;
  float s = 0.f;
  for (int b = 0; b < Bsz; b++) s += x[((size_t)b * Tsz + t) * Isz + k];
  float pr[3];
  #pragma unroll
  for (int qq = 0; qq < 3; qq++) pr[qq] = s * w_sel[qq * (Hsz + Isz) + Hsz + k];
  #pragma unroll
  for (int off = 32; off; off >>= 1)
    #pragma unroll
    for (int qq = 0; qq < 3; qq++) pr[qq] += __shfl_xor(pr[qq], off);
  __shared__ float red[4][3];
  const int wv = k >> 6, ln = k & 63;
  if (ln == 0) { red[wv][0] = pr[0]; red[wv][1] = pr[1]; red[wv][2] = pr[2]; }
  __syncthreads();
  if (k == 0) {
    #pragma unroll
    for (int qq = 0; qq < 3; qq++)
      xs[t * 3 + qq] = red[0][qq] + red[1][qq] + red[2][qq] + red[3][qq]
                      + (float)Bsz * b_sel[qq];
  }
}

// ---------------- serial selector chain ----------------
__global__ __launch_bounds__(256) void select_kernel(
    const float* __restrict__ score_h, const float* __restrict__ xs,
    int* __restrict__ cur)
{
  __shared__ int f[Tsz][3];
  const int tid = threadIdx.x;
  for (int u = tid; u < (Tsz - 1) * 3; u += 256) {
    const int t = 1 + u / 3, cc = u % 3;
    const float* sh = score_h + ((size_t)cc * Tsz + (t - 1)) * 3;
    const float* xr = xs + t * 3;
    const float v0 = sh[0] + xr[0];
    const float v1 = sh[1] + xr[1];
    const float v2 = sh[2] + xr[2];
    int best = 0; float bv = v0;
    if (v1 > bv) { bv = v1; best = 1; }
    if (v2 > bv) { bv = v2; best = 2; }
    f[t][cc] = best;
  }
  __syncthreads();
  if (tid == 0) {
    int cc = 0; cur[0] = 0;
    for (int t = 1; t < Tsz; t++) { cc = f[t][cc]; cur[t] = cc; }
  }
}

// ---------------- gather outputs ----------------
__global__ __launch_bounds__(256) void gather_out(
    const unsigned short* __restrict__ Hhi, const unsigned short* __restrict__ Hlo,
    const int* __restrict__ cur, float* __restrict__ out)
{
  const size_t idx = ((size_t)blockIdx.x * 256 + threadIdx.x) * 4;
  const size_t BTH = (size_t)Bsz * Tsz * Hsz;
  int b, t, h;
  if (idx < BTH) {
    b = (int)(idx >> 16);
    const int rem = (int)(idx & 65535);
    t = rem >> 8; h = rem & 255;
  } else {
    const size_t r2 = idx - BTH;
    b = (int)(r2 >> 8); h = (int)(r2 & 255); t = Tsz - 1;
  }
  const int cc = cur[t];
  const size_t g = (((size_t)cc * Mrows + (size_t)b * Tsz + t) * Hsz + h);
  const ushort4 vh = *(const ushort4*)(Hhi + g);
  const ushort4 vl = *(const ushort4*)(Hlo + g);
  float4 v;
  v.x = b2f(vh.x) + b2f(vl.x); v.y = b2f(vh.y) + b2f(vl.y);
  v.z = b2f(vh.z) + b2f(vl.z); v.w = b2f(vh.w) + b2f(vl.w);
  *(float4*)(out + idx) = v;
}

extern "C" void kernel_launch(void* const* d_in, const int* in_sizes, int n_in,
                              void* d_out, int out_size, void* d_ws, size_t ws_size,
                              hipStream_t stream) {
  const float* x      = (const float*)d_in[0];
  const float* hidden = (const float*)d_in[1];
  const float* w_ih0  = (const float*)d_in[2];
  const float* b_ih0  = (const float*)d_in[3];
  const float* b_hh0  = (const float*)d_in[4];
  const float* w_ih   = (const float*)d_in[5];
  const float* b_ih   = (const float*)d_in[6];
  const float* b_hh   = (const float*)d_in[7];
  const float* w_lw   = (const float*)d_in[8];
  const float* b_lw   = (const float*)d_in[9];
  const float* w_sel  = (const float*)d_in[10];
  const float* b_sel  = (const float*)d_in[11];
  float* out = (float*)d_out;

  char* w = (char*)d_ws;
  const size_t PLANE = (size_t)3 * Mrows * 256 * sizeof(unsigned short); // 50.3 MB
  unsigned short* HAhi = (unsigned short*)w; w += PLANE;
  unsigned short* HAlo = (unsigned short*)w; w += PLANE;
  unsigned short* HBhi = (unsigned short*)w; w += PLANE;
  unsigned short* HBlo = (unsigned short*)w; w += PLANE;
  const size_t W0N = (size_t)3 * 768 * 256;        // 589824
  const size_t WLN = (size_t)3 * 3 * 768 * 256;    // 1769472
  unsigned short* Whi0 = (unsigned short*)w; w += W0N * 2;
  unsigned short* Wlo0 = (unsigned short*)w; w += W0N * 2;
  unsigned short* Whi_ = (unsigned short*)w; w += WLN * 2;
  unsigned short* Wlo_ = (unsigned short*)w; w += WLN * 2;
  float* e       = (float*)w; w += (size_t)3 * Tsz * Bsz * 16 * 4;
  float* p       = (float*)w; w += (size_t)3 * Tsz * Bsz * 12 * 4;
  float* score_h = (float*)w; w += (size_t)3 * Tsz * 3 * 4;
  float* xsb     = (float*)w; w += (size_t)Tsz * 3 * 4;
  int*   curb    = (int*)w;   w += (size_t)Tsz * 4;

  // split weights into bf16 hi/lo planes
  split4_kernel<<<(int)(W0N / 4 + 255) / 256, 256, 0, stream>>>(w_ih0, Whi0, Wlo0, (int)(W0N / 4));
  split4_kernel<<<(int)(WLN / 4 + 255) / 256, 256, 0, stream>>>(w_ih, Whi_, Wlo_, (int)(WLN / 4));

  dim3 ggrid(Mrows / 128, 4, 3);

  // layer 0: A = x (fp32, shared across cur)
  gemm_gru_mfma<true><<<ggrid, 256, 0, stream>>>(
      x, nullptr, nullptr, (size_t)0,
      Whi0, Wlo0, (size_t)768 * 256,
      b_ih0, (size_t)768, b_hh0, (size_t)768, HAhi, HAlo);
  ep_kernel<<<(3 * Mrows) / 4, 256, 0, stream>>>(HAhi, HAlo, w_lw, w_sel, 0, e, p);

  const size_t wcur = (size_t)3 * 768 * 256;   // per-cur stride in w_ih planes
  const size_t bst  = (size_t)3 * 768;
  unsigned short* pingHi = HAhi; unsigned short* pingLo = HAlo;
  unsigned short* pongHi = HBhi; unsigned short* pongLo = HBlo;
  for (int l = 1; l < 4; l++) {
    gemm_gru_mfma<false><<<ggrid, 256, 0, stream>>>(
        nullptr, pingHi, pingLo, (size_t)Mrows * 256,
        Whi_ + (size_t)(l - 1) * 768 * 256, Wlo_ + (size_t)(l - 1) * 768 * 256, wcur,
        b_ih + (size_t)(l - 1) * 768, bst,
        b_hh + (size_t)(l - 1) * 768, bst, pongHi, pongLo);
    ep_kernel<<<(3 * Mrows) / 4, 256, 0, stream>>>(pongHi, pongLo, w_lw, w_sel, l, e, p);
    unsigned short* t1 = pingHi; pingHi = pongHi; pongHi = t1;
    unsigned short* t2 = pingLo; pingLo = pongLo; pongLo = t2;
  }
  // after loop, last-written planes are ping*
  attn_finish<<<dim3(Tsz, 3), 128, 0, stream>>>(e, p, hidden, b_lw, score_h);
  xs_kernel<<<Tsz, 256, 0, stream>>>(x, w_sel, b_sel, xsb);
  select_kernel<<<1, 256, 0, stream>>>(score_h, xsb, curb);
  gather_out<<<8224, 256, 0, stream>>>(pingHi, pingLo, curb, out);
}

// Round 3
// 657.186 us; speedup vs baseline: 3.4432x; 1.3601x over previous
//
#include <hip/hip_runtime.h>
#include <math.h>

#define Bsz 128
#define Tsz 256
#define Isz 256
#define Hsz 256
#define Lsz 4
#define Ssz 3
#define Mrows (Bsz*Tsz)   // 32768

using f16x8 = __attribute__((ext_vector_type(8))) _Float16;
using f32x4 = __attribute__((ext_vector_type(4))) float;

// ---------------- fp32 -> fp16 convert (8 elems/thread) ----------------
__global__ __launch_bounds__(256) void f32_to_f16(
    const float* __restrict__ src, _Float16* __restrict__ dst, int n8)
{
  const int idx = blockIdx.x * 256 + threadIdx.x;
  if (idx >= n8) return;
  const float4 v0 = *(const float4*)(src + (size_t)idx * 8);
  const float4 v1 = *(const float4*)(src + (size_t)idx * 8 + 4);
  _Float16 h[8];
  h[0] = (_Float16)v0.x; h[1] = (_Float16)v0.y;
  h[2] = (_Float16)v0.z; h[3] = (_Float16)v0.w;
  h[4] = (_Float16)v1.x; h[5] = (_Float16)v1.y;
  h[6] = (_Float16)v1.z; h[7] = (_Float16)v1.w;
  *(uint4*)(dst + (size_t)idx * 8) = *(uint4*)h;
}

// ---------------- fused GRU-layer GEMM, fp16 MFMA ----------------
// gi_slab = A @ W_slab^T (slabs r/z/n), gating fused, h written fp16.
// grid: (M/128, 256/64, 3 cur). block 256 = 4 waves.
__global__ __launch_bounds__(256, 3) void gemm_gru_f16(
    const _Float16* __restrict__ Abase, size_t a_cur_stride,
    const _Float16* __restrict__ Wbase, size_t w_cur_stride,
    const float* __restrict__ bi_g, size_t bi_stride,
    const float* __restrict__ bh_g, size_t bh_stride,
    _Float16* __restrict__ Hout)
{
  // chunk-major LDS, row-padding keeps b128 access conflict-minimal
  __shared__ _Float16 AhS[4 * 130 * 8];      // 8.3 KB
  __shared__ _Float16 WhS[3 * 4 * 66 * 8];   // 12.7 KB

  const int tid = threadIdx.x;
  const int cu  = blockIdx.z;
  const int m0  = blockIdx.x * 128;
  const int n0  = blockIdx.y * 64;

  const _Float16* A = Abase + (size_t)cu * a_cur_stride;
  const _Float16* W = Wbase + (size_t)cu * w_cur_stride;
  const float* bi = bi_g + (size_t)cu * bi_stride;
  const float* bh = bh_g + (size_t)cu * bh_stride;

  const int lane = tid & 63;
  const int wv   = tid >> 6;
  const int q    = lane >> 4;      // k-chunk within frag
  const int c    = lane & 15;      // row/col within frag
  const int mb   = wv * 32;        // wave's row base within 128-tile

  f32x4 acc[3][2][4];
  #pragma unroll
  for (int s = 0; s < 3; s++)
    #pragma unroll
    for (int mi = 0; mi < 2; mi++)
      #pragma unroll
      for (int ni = 0; ni < 4; ni++)
        acc[s][mi][ni] = (f32x4)0.f;

  for (int k0 = 0; k0 < 256; k0 += 32) {
    // stage A tile (128 x 32)
    #pragma unroll
    for (int i = 0; i < 2; i++) {
      const int idx = tid + i * 256;        // 0..511
      const int row = idx >> 2, ch = idx & 3;
      *(uint4*)&AhS[(ch * 130 + row) * 8] =
          *(const uint4*)(A + (size_t)(m0 + row) * 256 + k0 + ch * 8);
    }
    // stage W tiles (3 slabs x 64 x 32)
    #pragma unroll
    for (int i = 0; i < 3; i++) {
      const int idx = tid + i * 256;        // 0..767
      const int s = idx >> 8, rr = (idx >> 2) & 63, ch = idx & 3;
      *(uint4*)&WhS[((s * 4 + ch) * 66 + rr) * 8] =
          *(const uint4*)(W + (size_t)(s * 256 + n0 + rr) * 256 + k0 + ch * 8);
    }
    __syncthreads();

    const f16x8 a0 = *(const f16x8*)&AhS[(q * 130 + mb + c) * 8];
    const f16x8 a1 = *(const f16x8*)&AhS[(q * 130 + mb + 16 + c) * 8];

    #pragma unroll
    for (int s = 0; s < 3; s++) {
      #pragma unroll
      for (int ni = 0; ni < 4; ni++) {
        const f16x8 w = *(const f16x8*)&WhS[((s * 4 + q) * 66 + ni * 16 + c) * 8];
        acc[s][0][ni] = __builtin_amdgcn_mfma_f32_16x16x32_f16(a0, w, acc[s][0][ni], 0, 0, 0);
        acc[s][1][ni] = __builtin_amdgcn_mfma_f32_16x16x32_f16(a1, w, acc[s][1][ni], 0, 0, 0);
      }
    }
    __syncthreads();
  }

  // epilogue: gating, h stored as fp16
  float bir[4], biz[4], bin_[4], bhr[4], bhz[4], bhn[4];
  #pragma unroll
  for (int ni = 0; ni < 4; ni++) {
    const int n = n0 + ni * 16 + c;
    bir[ni]  = bi[n];       bhr[ni] = bh[n];
    biz[ni]  = bi[256 + n]; bhz[ni] = bh[256 + n];
    bin_[ni] = bi[512 + n]; bhn[ni] = bh[512 + n];
  }
  #pragma unroll
  for (int mi = 0; mi < 2; mi++) {
    #pragma unroll
    for (int reg = 0; reg < 4; reg++) {
      const int m = m0 + mb + mi * 16 + q * 4 + reg;
      const size_t rowbase = ((size_t)cu * Mrows + m) * 256;
      #pragma unroll
      for (int ni = 0; ni < 4; ni++) {
        const float gr = acc[0][mi][ni][reg] + bir[ni] + bhr[ni];
        const float gz = acc[1][mi][ni][reg] + biz[ni] + bhz[ni];
        const float gn = acc[2][mi][ni][reg] + bin_[ni];
        const float r  = 1.f / (1.f + expf(-gr));
        const float zz = 1.f / (1.f + expf(-gz));
        const float nn = tanhf(gn + r * bhn[ni]);
        Hout[rowbase + n0 + ni * 16 + c] = (_Float16)((1.f - zz) * nn);
      }
    }
  }
}

// ---------------- per-layer dot products (e, p) ----------------
__global__ __launch_bounds__(256) void ep_kernel(
    const _Float16* __restrict__ Hh,
    const float* __restrict__ w_lw, const float* __restrict__ w_sel, int layer,
    float* __restrict__ e, float* __restrict__ p)
{
  const int wv = threadIdx.x >> 6, ln = threadIdx.x & 63;
  const size_t mg = (size_t)blockIdx.x * 4 + wv;  // 0..3*M-1
  union { ushort4 u; _Float16 h[4]; } cv;
  cv.u = *(const ushort4*)(Hh + mg * 256 + ln * 4);
  float4 h;
  h.x = (float)cv.h[0]; h.y = (float)cv.h[1];
  h.z = (float)cv.h[2]; h.w = (float)cv.h[3];
  float d[7];
  #pragma unroll
  for (int j = 0; j < 4; j++) {
    const float4 w = *(const float4*)(w_lw + j * 256 + ln * 4);
    d[j] = h.x * w.x + h.y * w.y + h.z * w.z + h.w * w.w;
  }
  #pragma unroll
  for (int qq = 0; qq < 3; qq++) {
    const float4 w = *(const float4*)(w_sel + qq * (Hsz + Isz) + ln * 4);
    d[4 + qq] = h.x * w.x + h.y * w.y + h.z * w.z + h.w * w.w;
  }
  #pragma unroll
  for (int off = 32; off; off >>= 1)
    #pragma unroll
    for (int i = 0; i < 7; i++) d[i] += __shfl_xor(d[i], off);
  if (ln == 0) {
    const int cc = (int)(mg / Mrows);
    const int m = (int)(mg % Mrows);
    const int b = m >> 8, t = m & 255;
    const size_t base = ((size_t)cc * Tsz + t) * Bsz + b;
    #pragma unroll
    for (int j = 0; j < 4; j++) e[base * 16 + layer * 4 + j] = d[j];
    #pragma unroll
    for (int qq = 0; qq < 3; qq++) p[base * 12 + layer * 3 + qq] = d[4 + qq];
  }
}

// ---------------- softmax-attention + batch-reduced selector scores ----------------
__global__ __launch_bounds__(128) void attn_finish(
    const float* __restrict__ e, const float* __restrict__ p,
    const float* __restrict__ hidden, const float* __restrict__ b_lw,
    float* __restrict__ score_h)
{
  const int t = blockIdx.x, cc = blockIdx.y;
  const int b = threadIdx.x;
  const float* eb = e + ((size_t)(cc * Tsz + t) * Bsz + b) * 16;
  const float* pb = p + ((size_t)(cc * Tsz + t) * Bsz + b) * 12;
  const float* hb = hidden + b * 16;
  const float bl0 = b_lw[0], bl1 = b_lw[1], bl2 = b_lw[2], bl3 = b_lw[3];
  float attn[4];
  #pragma unroll
  for (int i = 0; i < 4; i++) {
    attn[i] = hb[i * 4 + 0] * (eb[i * 4 + 0] + bl0)
            + hb[i * 4 + 1] * (eb[i * 4 + 1] + bl1)
            + hb[i * 4 + 2] * (eb[i * 4 + 2] + bl2)
            + hb[i * 4 + 3] * (eb[i * 4 + 3] + bl3);
  }
  const float mx = fmaxf(fmaxf(attn[0], attn[1]), fmaxf(attn[2], attn[3]));
  float ex[4], sum = 0.f;
  #pragma unroll
  for (int i = 0; i < 4; i++) { ex[i] = expf(attn[i] - mx); sum += ex[i]; }
  const float inv = 1.f / sum;
  float sc[3];
  #pragma unroll
  for (int s = 0; s < 3; s++) {
    float v = 0.f;
    #pragma unroll
    for (int i = 0; i < 4; i++) v += ex[i] * pb[i * 3 + s];
    sc[s] = v * inv;
  }
  #pragma unroll
  for (int off = 32; off; off >>= 1)
    #pragma unroll
    for (int s = 0; s < 3; s++) sc[s] += __shfl_xor(sc[s], off);
  __shared__ float red[2][3];
  const int wv = threadIdx.x >> 6, ln = threadIdx.x & 63;
  if (ln == 0) { red[wv][0] = sc[0]; red[wv][1] = sc[1]; red[wv][2] = sc[2]; }
  __syncthreads();
  if (threadIdx.x == 0) {
    #pragma unroll
    for (int s = 0; s < 3; s++)
      score_h[((size_t)cc * Tsz + t) * 3 + s] = red[0][s] + red[1][s];
  }
}

// ---------------- xs[t,s] ----------------
__global__ __launch_bounds__(256) void xs_kernel(
    const float* __restrict__ x, const float* __restrict__ w_sel,
    const float* __restrict__ b_sel, float* __restrict__ xs)
{
  const int t = blockIdx.x, k = threadIdx.x;
  float s = 0.f;
  for (int b = 0; b < Bsz; b++) s += x[((size_t)b * Tsz + t) * Isz + k];
  float pr[3];
  #pragma unroll
  for (int qq = 0; qq < 3; qq++) pr[qq] = s * w_sel[qq * (Hsz + Isz) + Hsz + k];
  #pragma unroll
  for (int off = 32; off; off >>= 1)
    #pragma unroll
    for (int qq = 0; qq < 3; qq++) pr[qq] += __shfl_xor(pr[qq], off);
  __shared__ float red[4][3];
  const int wv = k >> 6, ln = k & 63;
  if (ln == 0) { red[wv][0] = pr[0]; red[wv][1] = pr[1]; red[wv][2] = pr[2]; }
  __syncthreads();
  if (k == 0) {
    #pragma unroll
    for (int qq = 0; qq < 3; qq++)
      xs[t * 3 + qq] = red[0][qq] + red[1][qq] + red[2][qq] + red[3][qq]
                      + (float)Bsz * b_sel[qq];
  }
}

// ---------------- serial selector chain ----------------
__global__ __launch_bounds__(256) void select_kernel(
    const float* __restrict__ score_h, const float* __restrict__ xs,
    int* __restrict__ cur)
{
  __shared__ int f[Tsz][3];
  const int tid = threadIdx.x;
  for (int u = tid; u < (Tsz - 1) * 3; u += 256) {
    const int t = 1 + u / 3, cc = u % 3;
    const float* sh = score_h + ((size_t)cc * Tsz + (t - 1)) * 3;
    const float* xr = xs + t * 3;
    const float v0 = sh[0] + xr[0];
    const float v1 = sh[1] + xr[1];
    const float v2 = sh[2] + xr[2];
    int best = 0; float bv = v0;
    if (v1 > bv) { bv = v1; best = 1; }
    if (v2 > bv) { bv = v2; best = 2; }
    f[t][cc] = best;
  }
  __syncthreads();
  if (tid == 0) {
    int cc = 0; cur[0] = 0;
    for (int t = 1; t < Tsz; t++) { cc = f[t][cc]; cur[t] = cc; }
  }
}

// ---------------- gather outputs (fp16 h -> fp32 out) ----------------
__global__ __launch_bounds__(256) void gather_out(
    const _Float16* __restrict__ Hh, const int* __restrict__ cur,
    float* __restrict__ out)
{
  const size_t idx = ((size_t)blockIdx.x * 256 + threadIdx.x) * 4;
  const size_t BTH = (size_t)Bsz * Tsz * Hsz;
  int b, t, h;
  if (idx < BTH) {
    b = (int)(idx >> 16);
    const int rem = (int)(idx & 65535);
    t = rem >> 8; h = rem & 255;
  } else {
    const size_t r2 = idx - BTH;
    b = (int)(r2 >> 8); h = (int)(r2 & 255); t = Tsz - 1;
  }
  const int cc = cur[t];
  const size_t g = (((size_t)cc * Mrows + (size_t)b * Tsz + t) * Hsz + h);
  union { ushort4 u; _Float16 hv[4]; } cv;
  cv.u = *(const ushort4*)(Hh + g);
  float4 v;
  v.x = (float)cv.hv[0]; v.y = (float)cv.hv[1];
  v.z = (float)cv.hv[2]; v.w = (float)cv.hv[3];
  *(float4*)(out + idx) = v;
}

extern "C" void kernel_launch(void* const* d_in, const int* in_sizes, int n_in,
                              void* d_out, int out_size, void* d_ws, size_t ws_size,
                              hipStream_t stream) {
  const float* x      = (const float*)d_in[0];
  const float* hidden = (const float*)d_in[1];
  const float* w_ih0  = (const float*)d_in[2];
  const float* b_ih0  = (const float*)d_in[3];
  const float* b_hh0  = (const float*)d_in[4];
  const float* w_ih   = (const float*)d_in[5];
  const float* b_ih   = (const float*)d_in[6];
  const float* b_hh   = (const float*)d_in[7];
  const float* w_lw   = (const float*)d_in[8];
  const float* b_lw   = (const float*)d_in[9];
  const float* w_sel  = (const float*)d_in[10];
  const float* b_sel  = (const float*)d_in[11];
  float* out = (float*)d_out;

  char* w = (char*)d_ws;
  const size_t HN = (size_t)3 * Mrows * 256;       // 25.2M
  const size_t XN = (size_t)Bsz * Tsz * Isz;       // 8.39M
  const size_t W0N = (size_t)3 * 768 * 256;        // 589824
  const size_t WLN = (size_t)3 * 3 * 768 * 256;    // 1769472
  _Float16* HA  = (_Float16*)w; w += HN * 2;
  _Float16* HB  = (_Float16*)w; w += HN * 2;
  _Float16* xh  = (_Float16*)w; w += XN * 2;
  _Float16* Wh0 = (_Float16*)w; w += W0N * 2;
  _Float16* WhL = (_Float16*)w; w += WLN * 2;
  float* e       = (float*)w; w += (size_t)3 * Tsz * Bsz * 16 * 4;
  float* p       = (float*)w; w += (size_t)3 * Tsz * Bsz * 12 * 4;
  float* score_h = (float*)w; w += (size_t)3 * Tsz * 3 * 4;
  float* xsb     = (float*)w; w += (size_t)Tsz * 3 * 4;
  int*   curb    = (int*)w;   w += (size_t)Tsz * 4;

  // fp32 -> fp16 conversions
  f32_to_f16<<<(int)(XN / 8 + 255) / 256, 256, 0, stream>>>(x, xh, (int)(XN / 8));
  f32_to_f16<<<(int)(W0N / 8 + 255) / 256, 256, 0, stream>>>(w_ih0, Wh0, (int)(W0N / 8));
  f32_to_f16<<<(int)(WLN / 8 + 255) / 256, 256, 0, stream>>>(w_ih, WhL, (int)(WLN / 8));

  dim3 ggrid(Mrows / 128, 4, 3);

  // layer 0: A = xh (shared across cur)
  gemm_gru_f16<<<ggrid, 256, 0, stream>>>(
      xh, (size_t)0, Wh0, (size_t)768 * 256,
      b_ih0, (size_t)768, b_hh0, (size_t)768, HA);
  ep_kernel<<<(3 * Mrows) / 4, 256, 0, stream>>>(HA, w_lw, w_sel, 0, e, p);

  const size_t wcur = (size_t)3 * 768 * 256;
  const size_t bst  = (size_t)3 * 768;
  _Float16* ping = HA; _Float16* pong = HB;
  for (int l = 1; l < 4; l++) {
    gemm_gru_f16<<<ggrid, 256, 0, stream>>>(
        ping, (size_t)Mrows * 256,
        WhL + (size_t)(l - 1) * 768 * 256, wcur,
        b_ih + (size_t)(l - 1) * 768, bst,
        b_hh + (size_t)(l - 1) * 768, bst, pong);
    ep_kernel<<<(3 * Mrows) / 4, 256, 0, stream>>>(pong, w_lw, w_sel, l, e, p);
    _Float16* t1 = ping; ping = pong; pong = t1;
  }

  attn_finish<<<dim3(Tsz, 3), 128, 0, stream>>>(e, p, hidden, b_lw, score_h);
  xs_kernel<<<Tsz, 256, 0, stream>>>(x, w_sel, b_sel, xsb);
  select_kernel<<<1, 256, 0, stream>>>(score_h, xsb, curb);
  gather_out<<<8224, 256, 0, stream>>>(ping, curb, out);
}

// Round 4
// 532.261 us; speedup vs baseline: 4.2513x; 1.2347x over previous
//
#include <hip/hip_runtime.h>
#include <math.h>

#define Bsz 128
#define Tsz 256
#define Isz 256
#define Hsz 256
#define Lsz 4
#define Ssz 3
#define Mrows (Bsz*Tsz)   // 32768

using f16x8 = __attribute__((ext_vector_type(8))) _Float16;
using f32x4 = __attribute__((ext_vector_type(4))) float;

__device__ inline float fast_sig(float x) { return 1.f / (1.f + __expf(-x)); }
__device__ inline float fast_tanh(float x) {
  const float e = __expf(-2.f * fabsf(x));
  const float y = (1.f - e) / (1.f + e);
  return x < 0.f ? -y : y;
}

// ---------------- fp32 -> fp16 convert (8 elems/thread) ----------------
__global__ __launch_bounds__(256) void f32_to_f16(
    const float* __restrict__ src, _Float16* __restrict__ dst, int n8)
{
  const int idx = blockIdx.x * 256 + threadIdx.x;
  if (idx >= n8) return;
  const float4 v0 = *(const float4*)(src + (size_t)idx * 8);
  const float4 v1 = *(const float4*)(src + (size_t)idx * 8 + 4);
  _Float16 h[8];
  h[0] = (_Float16)v0.x; h[1] = (_Float16)v0.y;
  h[2] = (_Float16)v0.z; h[3] = (_Float16)v0.w;
  h[4] = (_Float16)v1.x; h[5] = (_Float16)v1.y;
  h[6] = (_Float16)v1.z; h[7] = (_Float16)v1.w;
  *(uint4*)(dst + (size_t)idx * 8) = *(uint4*)h;
}

// ---------------- fused GRU-layer GEMM, fp16 MFMA ----------------
// gi_slab = A @ W_slab^T (slabs r/z/n), gating fused, h written fp16.
// grid: (M/128, 256/64, 3 cur). block 256 = 4 waves.
__global__ __launch_bounds__(256, 3) void gemm_gru_f16(
    const _Float16* __restrict__ Abase, size_t a_cur_stride,
    const _Float16* __restrict__ Wbase, size_t w_cur_stride,
    const float* __restrict__ bi_g, size_t bi_stride,
    const float* __restrict__ bh_g, size_t bh_stride,
    _Float16* __restrict__ Hout)
{
  __shared__ _Float16 AhS[4 * 130 * 8];      // 8.3 KB
  __shared__ _Float16 WhS[3 * 4 * 66 * 8];   // 12.7 KB

  const int tid = threadIdx.x;
  const int cu  = blockIdx.z;
  const int m0  = blockIdx.x * 128;
  const int n0  = blockIdx.y * 64;

  const _Float16* A = Abase + (size_t)cu * a_cur_stride;
  const _Float16* W = Wbase + (size_t)cu * w_cur_stride;
  const float* bi = bi_g + (size_t)cu * bi_stride;
  const float* bh = bh_g + (size_t)cu * bh_stride;

  const int lane = tid & 63;
  const int wv   = tid >> 6;
  const int q    = lane >> 4;      // k-chunk within frag
  const int c    = lane & 15;      // row/col within frag
  const int mb   = wv * 32;        // wave's row base within 128-tile

  f32x4 acc[3][2][4];
  #pragma unroll
  for (int s = 0; s < 3; s++)
    #pragma unroll
    for (int mi = 0; mi < 2; mi++)
      #pragma unroll
      for (int ni = 0; ni < 4; ni++)
        acc[s][mi][ni] = (f32x4)0.f;

  for (int k0 = 0; k0 < 256; k0 += 32) {
    // stage A tile (128 x 32)
    #pragma unroll
    for (int i = 0; i < 2; i++) {
      const int idx = tid + i * 256;        // 0..511
      const int row = idx >> 2, ch = idx & 3;
      *(uint4*)&AhS[(ch * 130 + row) * 8] =
          *(const uint4*)(A + (size_t)(m0 + row) * 256 + k0 + ch * 8);
    }
    // stage W tiles (3 slabs x 64 x 32)
    #pragma unroll
    for (int i = 0; i < 3; i++) {
      const int idx = tid + i * 256;        // 0..767
      const int s = idx >> 8, rr = (idx >> 2) & 63, ch = idx & 3;
      *(uint4*)&WhS[((s * 4 + ch) * 66 + rr) * 8] =
          *(const uint4*)(W + (size_t)(s * 256 + n0 + rr) * 256 + k0 + ch * 8);
    }
    __syncthreads();

    const f16x8 a0 = *(const f16x8*)&AhS[(q * 130 + mb + c) * 8];
    const f16x8 a1 = *(const f16x8*)&AhS[(q * 130 + mb + 16 + c) * 8];

    #pragma unroll
    for (int s = 0; s < 3; s++) {
      #pragma unroll
      for (int ni = 0; ni < 4; ni++) {
        const f16x8 w = *(const f16x8*)&WhS[((s * 4 + q) * 66 + ni * 16 + c) * 8];
        acc[s][0][ni] = __builtin_amdgcn_mfma_f32_16x16x32_f16(a0, w, acc[s][0][ni], 0, 0, 0);
        acc[s][1][ni] = __builtin_amdgcn_mfma_f32_16x16x32_f16(a1, w, acc[s][1][ni], 0, 0, 0);
      }
    }
    __syncthreads();
  }

  // epilogue: gating with fast native transcendentals, h stored fp16
  float bir[4], biz[4], bin_[4], bhr[4], bhz[4], bhn[4];
  #pragma unroll
  for (int ni = 0; ni < 4; ni++) {
    const int n = n0 + ni * 16 + c;
    bir[ni]  = bi[n];       bhr[ni] = bh[n];
    biz[ni]  = bi[256 + n]; bhz[ni] = bh[256 + n];
    bin_[ni] = bi[512 + n]; bhn[ni] = bh[512 + n];
  }
  #pragma unroll
  for (int mi = 0; mi < 2; mi++) {
    #pragma unroll
    for (int reg = 0; reg < 4; reg++) {
      const int m = m0 + mb + mi * 16 + q * 4 + reg;
      const size_t rowbase = ((size_t)cu * Mrows + m) * 256;
      #pragma unroll
      for (int ni = 0; ni < 4; ni++) {
        const float gr = acc[0][mi][ni][reg] + bir[ni] + bhr[ni];
        const float gz = acc[1][mi][ni][reg] + biz[ni] + bhz[ni];
        const float gn = acc[2][mi][ni][reg] + bin_[ni];
        const float r  = fast_sig(gr);
        const float zz = fast_sig(gz);
        const float nn = fast_tanh(gn + r * bhn[ni]);
        Hout[rowbase + n0 + ni * 16 + c] = (_Float16)((1.f - zz) * nn);
      }
    }
  }
}

// ---------------- per-layer dot products (e, p), block-tiled ----------------
// 64 rows/block; thread (r, pp) accumulates 7 dots over K-quarter pp in regs.
__global__ __launch_bounds__(256) void ep_tile(
    const _Float16* __restrict__ Hh,
    const float* __restrict__ w_lw, const float* __restrict__ w_sel, int layer,
    float* __restrict__ e, float* __restrict__ p)
{
  __shared__ _Float16 hs[64 * 264];   // 33 KB, padded stride
  __shared__ float wc[7][256];        // 7 KB
  __shared__ float ps[4][64][8];      // 8 KB partials
  const int tid = threadIdx.x;
  const size_t mg0 = (size_t)blockIdx.x * 64;

  // stage h tile (coalesced)
  #pragma unroll
  for (int i = 0; i < 8; i++) {
    const int ci = tid + i * 256;          // 0..2047 chunks of 16B
    const int row = ci >> 5, kc = ci & 31;
    *(uint4*)&hs[row * 264 + kc * 8] =
        *(const uint4*)(Hh + (mg0 + row) * 256 + kc * 8);
  }
  // stage weight block: rows 0-3 = w_lw, 4-6 = w_sel[:, 0:256]
  #pragma unroll
  for (int j = 0; j < 7; j++)
    wc[j][tid] = (j < 4) ? w_lw[j * 256 + tid] : w_sel[(j - 4) * 512 + tid];
  __syncthreads();

  const int r = tid & 63, pp = tid >> 6;
  float acc[7] = {0.f, 0.f, 0.f, 0.f, 0.f, 0.f, 0.f};
  #pragma unroll
  for (int i = 0; i < 8; i++) {
    union { uint4 u; _Float16 h[8]; } hv;
    hv.u = *(uint4*)&hs[r * 264 + pp * 64 + i * 8];
    float hf[8];
    #pragma unroll
    for (int k = 0; k < 8; k++) hf[k] = (float)hv.h[k];
    #pragma unroll
    for (int j = 0; j < 7; j++) {
      const float4 w0 = *(const float4*)&wc[j][pp * 64 + i * 8];
      const float4 w1 = *(const float4*)&wc[j][pp * 64 + i * 8 + 4];
      acc[j] += hf[0] * w0.x + hf[1] * w0.y + hf[2] * w0.z + hf[3] * w0.w
              + hf[4] * w1.x + hf[5] * w1.y + hf[6] * w1.z + hf[7] * w1.w;
    }
  }
  #pragma unroll
  for (int j = 0; j < 7; j++) ps[pp][r][j] = acc[j];
  __syncthreads();

  if (tid < 64) {
    float d[7];
    #pragma unroll
    for (int j = 0; j < 7; j++)
      d[j] = ps[0][tid][j] + ps[1][tid][j] + ps[2][tid][j] + ps[3][tid][j];
    const size_t mg = mg0 + tid;
    const int cc = (int)(mg >> 15);          // / Mrows
    const int m  = (int)(mg & 32767);
    const int b = m >> 8, t = m & 255;
    const size_t base = ((size_t)cc * Tsz + t) * Bsz + b;
    #pragma unroll
    for (int j = 0; j < 4; j++) e[base * 16 + layer * 4 + j] = d[j];
    #pragma unroll
    for (int j = 0; j < 3; j++) p[base * 12 + layer * 3 + j] = d[4 + j];
  }
}

// ---------------- softmax-attention + batch-reduced selector scores ----------------
__global__ __launch_bounds__(128) void attn_finish(
    const float* __restrict__ e, const float* __restrict__ p,
    const float* __restrict__ hidden, const float* __restrict__ b_lw,
    float* __restrict__ score_h)
{
  const int t = blockIdx.x, cc = blockIdx.y;
  const int b = threadIdx.x;
  const float* eb = e + ((size_t)(cc * Tsz + t) * Bsz + b) * 16;
  const float* pb = p + ((size_t)(cc * Tsz + t) * Bsz + b) * 12;
  const float* hb = hidden + b * 16;
  const float bl0 = b_lw[0], bl1 = b_lw[1], bl2 = b_lw[2], bl3 = b_lw[3];
  float attn[4];
  #pragma unroll
  for (int i = 0; i < 4; i++) {
    attn[i] = hb[i * 4 + 0] * (eb[i * 4 + 0] + bl0)
            + hb[i * 4 + 1] * (eb[i * 4 + 1] + bl1)
            + hb[i * 4 + 2] * (eb[i * 4 + 2] + bl2)
            + hb[i * 4 + 3] * (eb[i * 4 + 3] + bl3);
  }
  const float mx = fmaxf(fmaxf(attn[0], attn[1]), fmaxf(attn[2], attn[3]));
  float ex[4], sum = 0.f;
  #pragma unroll
  for (int i = 0; i < 4; i++) { ex[i] = expf(attn[i] - mx); sum += ex[i]; }
  const float inv = 1.f / sum;
  float sc[3];
  #pragma unroll
  for (int s = 0; s < 3; s++) {
    float v = 0.f;
    #pragma unroll
    for (int i = 0; i < 4; i++) v += ex[i] * pb[i * 3 + s];
    sc[s] = v * inv;
  }
  #pragma unroll
  for (int off = 32; off; off >>= 1)
    #pragma unroll
    for (int s = 0; s < 3; s++) sc[s] += __shfl_xor(sc[s], off);
  __shared__ float red[2][3];
  const int wv = threadIdx.x >> 6, ln = threadIdx.x & 63;
  if (ln == 0) { red[wv][0] = sc[0]; red[wv][1] = sc[1]; red[wv][2] = sc[2]; }
  __syncthreads();
  if (threadIdx.x == 0) {
    #pragma unroll
    for (int s = 0; s < 3; s++)
      score_h[((size_t)cc * Tsz + t) * 3 + s] = red[0][s] + red[1][s];
  }
}

// ---------------- xs[t,s] ----------------
__global__ __launch_bounds__(256) void xs_kernel(
    const float* __restrict__ x, const float* __restrict__ w_sel,
    const float* __restrict__ b_sel, float* __restrict__ xs)
{
  const int t = blockIdx.x, k = threadIdx.x;
  float s = 0.f;
  for (int b = 0; b < Bsz; b++) s += x[((size_t)b * Tsz + t) * Isz + k];
  float pr[3];
  #pragma unroll
  for (int qq = 0; qq < 3; qq++) pr[qq] = s * w_sel[qq * (Hsz + Isz) + Hsz + k];
  #pragma unroll
  for (int off = 32; off; off >>= 1)
    #pragma unroll
    for (int qq = 0; qq < 3; qq++) pr[qq] += __shfl_xor(pr[qq], off);
  __shared__ float red[4][3];
  const int wv = k >> 6, ln = k & 63;
  if (ln == 0) { red[wv][0] = pr[0]; red[wv][1] = pr[1]; red[wv][2] = pr[2]; }
  __syncthreads();
  if (k == 0) {
    #pragma unroll
    for (int qq = 0; qq < 3; qq++)
      xs[t * 3 + qq] = red[0][qq] + red[1][qq] + red[2][qq] + red[3][qq]
                      + (float)Bsz * b_sel[qq];
  }
}

// ---------------- serial selector chain ----------------
__global__ __launch_bounds__(256) void select_kernel(
    const float* __restrict__ score_h, const float* __restrict__ xs,
    int* __restrict__ cur)
{
  __shared__ int f[Tsz][3];
  const int tid = threadIdx.x;
  for (int u = tid; u < (Tsz - 1) * 3; u += 256) {
    const int t = 1 + u / 3, cc = u % 3;
    const float* sh = score_h + ((size_t)cc * Tsz + (t - 1)) * 3;
    const float* xr = xs + t * 3;
    const float v0 = sh[0] + xr[0];
    const float v1 = sh[1] + xr[1];
    const float v2 = sh[2] + xr[2];
    int best = 0; float bv = v0;
    if (v1 > bv) { bv = v1; best = 1; }
    if (v2 > bv) { bv = v2; best = 2; }
    f[t][cc] = best;
  }
  __syncthreads();
  if (tid == 0) {
    int cc = 0; cur[0] = 0;
    for (int t = 1; t < Tsz; t++) { cc = f[t][cc]; cur[t] = cc; }
  }
}

// ---------------- gather outputs (fp16 h -> fp32 out) ----------------
__global__ __launch_bounds__(256) void gather_out(
    const _Float16* __restrict__ Hh, const int* __restrict__ cur,
    float* __restrict__ out)
{
  const size_t idx = ((size_t)blockIdx.x * 256 + threadIdx.x) * 4;
  const size_t BTH = (size_t)Bsz * Tsz * Hsz;
  int b, t, h;
  if (idx < BTH) {
    b = (int)(idx >> 16);
    const int rem = (int)(idx & 65535);
    t = rem >> 8; h = rem & 255;
  } else {
    const size_t r2 = idx - BTH;
    b = (int)(r2 >> 8); h = (int)(r2 & 255); t = Tsz - 1;
  }
  const int cc = cur[t];
  const size_t g = (((size_t)cc * Mrows + (size_t)b * Tsz + t) * Hsz + h);
  union { ushort4 u; _Float16 hv[4]; } cv;
  cv.u = *(const ushort4*)(Hh + g);
  float4 v;
  v.x = (float)cv.hv[0]; v.y = (float)cv.hv[1];
  v.z = (float)cv.hv[2]; v.w = (float)cv.hv[3];
  *(float4*)(out + idx) = v;
}

extern "C" void kernel_launch(void* const* d_in, const int* in_sizes, int n_in,
                              void* d_out, int out_size, void* d_ws, size_t ws_size,
                              hipStream_t stream) {
  const float* x      = (const float*)d_in[0];
  const float* hidden = (const float*)d_in[1];
  const float* w_ih0  = (const float*)d_in[2];
  const float* b_ih0  = (const float*)d_in[3];
  const float* b_hh0  = (const float*)d_in[4];
  const float* w_ih   = (const float*)d_in[5];
  const float* b_ih   = (const float*)d_in[6];
  const float* b_hh   = (const float*)d_in[7];
  const float* w_lw   = (const float*)d_in[8];
  const float* b_lw   = (const float*)d_in[9];
  const float* w_sel  = (const float*)d_in[10];
  const float* b_sel  = (const float*)d_in[11];
  float* out = (float*)d_out;

  char* w = (char*)d_ws;
  const size_t HN = (size_t)3 * Mrows * 256;       // 25.2M
  const size_t XN = (size_t)Bsz * Tsz * Isz;       // 8.39M
  const size_t W0N = (size_t)3 * 768 * 256;        // 589824
  const size_t WLN = (size_t)3 * 3 * 768 * 256;    // 1769472
  _Float16* HA  = (_Float16*)w; w += HN * 2;
  _Float16* HB  = (_Float16*)w; w += HN * 2;
  _Float16* xh  = (_Float16*)w; w += XN * 2;
  _Float16* Wh0 = (_Float16*)w; w += W0N * 2;
  _Float16* WhL = (_Float16*)w; w += WLN * 2;
  float* e       = (float*)w; w += (size_t)3 * Tsz * Bsz * 16 * 4;
  float* p       = (float*)w; w += (size_t)3 * Tsz * Bsz * 12 * 4;
  float* score_h = (float*)w; w += (size_t)3 * Tsz * 3 * 4;
  float* xsb     = (float*)w; w += (size_t)Tsz * 3 * 4;
  int*   curb    = (int*)w;   w += (size_t)Tsz * 4;

  // fp32 -> fp16 conversions
  f32_to_f16<<<(int)(XN / 8 + 255) / 256, 256, 0, stream>>>(x, xh, (int)(XN / 8));
  f32_to_f16<<<(int)(W0N / 8 + 255) / 256, 256, 0, stream>>>(w_ih0, Wh0, (int)(W0N / 8));
  f32_to_f16<<<(int)(WLN / 8 + 255) / 256, 256, 0, stream>>>(w_ih, WhL, (int)(WLN / 8));

  dim3 ggrid(Mrows / 128, 4, 3);

  // layer 0: A = xh (shared across cur)
  gemm_gru_f16<<<ggrid, 256, 0, stream>>>(
      xh, (size_t)0, Wh0, (size_t)768 * 256,
      b_ih0, (size_t)768, b_hh0, (size_t)768, HA);
  ep_tile<<<(3 * Mrows) / 64, 256, 0, stream>>>(HA, w_lw, w_sel, 0, e, p);

  const size_t wcur = (size_t)3 * 768 * 256;
  const size_t bst  = (size_t)3 * 768;
  _Float16* ping = HA; _Float16* pong = HB;
  for (int l = 1; l < 4; l++) {
    gemm_gru_f16<<<ggrid, 256, 0, stream>>>(
        ping, (size_t)Mrows * 256,
        WhL + (size_t)(l - 1) * 768 * 256, wcur,
        b_ih + (size_t)(l - 1) * 768, bst,
        b_hh + (size_t)(l - 1) * 768, bst, pong);
    ep_tile<<<(3 * Mrows) / 64, 256, 0, stream>>>(pong, w_lw, w_sel, l, e, p);
    _Float16* t1 = ping; ping = pong; pong = t1;
  }

  attn_finish<<<dim3(Tsz, 3), 128, 0, stream>>>(e, p, hidden, b_lw, score_h);
  xs_kernel<<<Tsz, 256, 0, stream>>>(x, w_sel, b_sel, xsb);
  select_kernel<<<1, 256, 0, stream>>>(score_h, xsb, curb);
  gather_out<<<8224, 256, 0, stream>>>(ping, curb, out);
}